// Round 15
// baseline (398.733 us; speedup 1.0000x reference)
//
#include <hip/hip_runtime.h>
#include <cstdint>
#include <cstddef>

#define N_ 4
#define L_ 1024
#define D_ 1024
#define H_ 16
#define HS_ 64
#define M_ (N_*L_)       // 4096 rows
#define DD_ (D_*D_)      // 1048576
#define MD_ ((size_t)M_*D_)

typedef unsigned short u16;
typedef __bf16 b16x8 __attribute__((ext_vector_type(8)));
typedef float f32x4 __attribute__((ext_vector_type(4)));

__device__ __forceinline__ float sigmoidf_(float x) { return 1.0f / (1.0f + __expf(-x)); }
__device__ __forceinline__ u16 f2bf(float f) {
    union { float f; uint32_t u; } c; c.f = f;
    uint32_t u = c.u;
    u += 0x7fffu + ((u >> 16) & 1u);   // RNE
    return (u16)(u >> 16);
}
__device__ __forceinline__ float bf2f(u16 u) {
    union { uint32_t u; float f; } c; c.u = ((uint32_t)u) << 16; return c.f;
}

// async global->LDS, 16B per lane
__device__ __forceinline__ void gl_lds16(const void* g, void* l) {
    auto gp = reinterpret_cast<const __attribute__((address_space(1))) unsigned int*>(
        reinterpret_cast<uintptr_t>(g));
    auto lp = reinterpret_cast<__attribute__((address_space(3))) unsigned int*>(
        reinterpret_cast<uintptr_t>(l));
    __builtin_amdgcn_global_load_lds(gp, lp, 16, 0, 0);
}

// ---------------- one-shot weight prep + query cvt: all bf16 ----------------
// ws0 layout (u16): Wop[DD] Wfc[DD] WQKV[16384] G1rz[4DD] G1h[2DD] G2rz[4DD] G2h[2DD]
__global__ __launch_bounds__(256) void prep_weights_kernel(
    const float* __restrict__ w_out, const float* __restrict__ fc_w,
    const float* __restrict__ wq, const float* __restrict__ wk, const float* __restrict__ wv,
    const float* __restrict__ g1W, const float* __restrict__ g1U,
    const float* __restrict__ g2W, const float* __restrict__ g2U,
    const float* __restrict__ query, u16* __restrict__ Xq,
    u16* __restrict__ ws0) {
    u16* Wop = ws0;
    u16* Wfc = ws0 + (size_t)DD_;
    u16* WQKV = ws0 + 2 * (size_t)DD_;
    u16* G1rz = WQKV + 16384;
    u16* G1h = G1rz + 4 * (size_t)DD_;
    u16* G2rz = G1h + 2 * (size_t)DD_;
    u16* G2h = G2rz + 4 * (size_t)DD_;
    int b = blockIdx.x, t = threadIdx.x;
    const float* src; u16* dst; size_t si, di;
    if (b < 512) {
        size_t f = (size_t)b * 2048 + t * 8; src = w_out; si = f; dst = Wop; di = f;
    } else if (b < 1024) {
        size_t f = (size_t)(b - 512) * 2048 + t * 8; src = fc_w; si = f; dst = Wfc; di = f;
    } else if (b < 1030) {
        size_t f = (size_t)(b - 1024) * 2048 + t * 8;
        int which = (int)(f >> 12); size_t off = f & 4095;
        src = which == 0 ? wq : (which == 1 ? wk : wv); si = off; dst = WQKV; di = f;
    } else if (b < 3078) {
        size_t f = (size_t)(b - 1030) * 2048 + t * 8;
        size_t row = f >> 11, k = f & 2047; size_t n2 = (row >= 1024) ? 1 : 0;
        src = (k < 1024) ? (g1W + n2 * DD_) : (g1U + n2 * DD_);
        si = (row & 1023) * 1024 + (k & 1023); dst = G1rz; di = f;
    } else if (b < 4102) {
        size_t f = (size_t)(b - 3078) * 2048 + t * 8;
        size_t row = f >> 11, k = f & 2047;
        src = (k < 1024) ? (g1W + 2 * (size_t)DD_) : (g1U + 2 * (size_t)DD_);
        si = row * 1024 + (k & 1023); dst = G1h; di = f;
    } else if (b < 6150) {
        size_t f = (size_t)(b - 4102) * 2048 + t * 8;
        size_t row = f >> 11, k = f & 2047; size_t n2 = (row >= 1024) ? 1 : 0;
        src = (k < 1024) ? (g2W + n2 * DD_) : (g2U + n2 * DD_);
        si = (row & 1023) * 1024 + (k & 1023); dst = G2rz; di = f;
    } else if (b < 7174) {
        size_t f = (size_t)(b - 6150) * 2048 + t * 8;
        size_t row = f >> 11, k = f & 2047;
        src = (k < 1024) ? (g2W + 2 * (size_t)DD_) : (g2U + 2 * (size_t)DD_);
        si = row * 1024 + (k & 1023); dst = G2h; di = f;
    } else {
        size_t f = (size_t)(b - 7174) * 2048 + t * 8;
        src = query; si = f; dst = Xq; di = f;
    }
    float4 a = *(const float4*)&src[si];
    float4 b4 = *(const float4*)&src[si + 4];
    u16 o[8] = { f2bf(a.x), f2bf(a.y), f2bf(a.z), f2bf(a.w),
                 f2bf(b4.x), f2bf(b4.y), f2bf(b4.z), f2bf(b4.w) };
    *(uint4*)&dst[di] = *(uint4*)o;
}

// ---------------- LayerNorm -> bf16 (blockIdx.y selects stream 0/1) ----------------
__global__ __launch_bounds__(256) void ln2in1_kernel(const float* __restrict__ x0, u16* __restrict__ y0,
                                                     const float* __restrict__ sc0, const float* __restrict__ bi0,
                                                     const float* __restrict__ x1, u16* __restrict__ y1,
                                                     const float* __restrict__ sc1, const float* __restrict__ bi1) {
    int row = blockIdx.x;
    const float* x = blockIdx.y ? x1 : x0;
    u16* y = blockIdx.y ? y1 : y0;
    const float* sc = blockIdx.y ? sc1 : sc0;
    const float* bi = blockIdx.y ? bi1 : bi0;
    const float* xr = x + (size_t)row * D_;
    int t = threadIdx.x;
    float4 v = *(const float4*)&xr[t * 4];
    float s = v.x + v.y + v.z + v.w;
    float q = v.x * v.x + v.y * v.y + v.z * v.z + v.w * v.w;
#pragma unroll
    for (int o = 32; o > 0; o >>= 1) { s += __shfl_xor(s, o); q += __shfl_xor(q, o); }
    __shared__ float ss[4], sq[4];
    int w = t >> 6;
    if ((t & 63) == 0) { ss[w] = s; sq[w] = q; }
    __syncthreads();
    s = ss[0] + ss[1] + ss[2] + ss[3];
    q = sq[0] + sq[1] + sq[2] + sq[3];
    float mean = s * (1.0f / D_);
    float var = q * (1.0f / D_) - mean * mean;
    float inv = rsqrtf(var + 1e-5f);
    float4 sv = *(const float4*)&sc[t * 4];
    float4 bv = *(const float4*)&bi[t * 4];
    u16 ov[4] = { f2bf((v.x - mean) * inv * sv.x + bv.x),
                  f2bf((v.y - mean) * inv * sv.y + bv.y),
                  f2bf((v.z - mean) * inv * sv.z + bv.z),
                  f2bf((v.w - mean) * inv * sv.w + bv.w) };
    *(ushort4*)&y[(size_t)row * D_ + t * 4] = *(ushort4*)ov;
}

// ---------------- single LayerNorm -> bf16 (ln2) ----------------
__global__ __launch_bounds__(256) void ln_kernel(const float* __restrict__ x, u16* __restrict__ y,
                                                 const float* __restrict__ sc, const float* __restrict__ bi) {
    int row = blockIdx.x;
    const float* xr = x + (size_t)row * D_;
    int t = threadIdx.x;
    float4 v = *(const float4*)&xr[t * 4];
    float s = v.x + v.y + v.z + v.w;
    float q = v.x * v.x + v.y * v.y + v.z * v.z + v.w * v.w;
#pragma unroll
    for (int o = 32; o > 0; o >>= 1) { s += __shfl_xor(s, o); q += __shfl_xor(q, o); }
    __shared__ float ss[4], sq[4];
    int w = t >> 6;
    if ((t & 63) == 0) { ss[w] = s; sq[w] = q; }
    __syncthreads();
    s = ss[0] + ss[1] + ss[2] + ss[3];
    q = sq[0] + sq[1] + sq[2] + sq[3];
    float mean = s * (1.0f / D_);
    float var = q * (1.0f / D_) - mean * mean;
    float inv = rsqrtf(var + 1e-5f);
    float4 sv = *(const float4*)&sc[t * 4];
    float4 bv = *(const float4*)&bi[t * 4];
    u16 ov[4] = { f2bf((v.x - mean) * inv * sv.x + bv.x),
                  f2bf((v.y - mean) * inv * sv.y + bv.y),
                  f2bf((v.z - mean) * inv * sv.z + bv.z),
                  f2bf((v.w - mean) * inv * sv.w + bv.w) };
    *(ushort4*)&y[(size_t)row * D_ + t * 4] = *(ushort4*)ov;
}

// -------- MFMA per-head projections: qh/kh row-major + vt transposed, all bf16 --------
__global__ __launch_bounds__(256) void proj_mfma_kernel(const u16* __restrict__ qbf,
                                                        const u16* __restrict__ vbf,
                                                        const u16* __restrict__ wqkv,
                                                        u16* __restrict__ qh, u16* __restrict__ kh,
                                                        u16* __restrict__ vt) {
    int t = threadIdx.x, w = t >> 6, l = t & 63;
    int lr = l & 15, lg = l >> 4;
    int rb = blockIdx.x, h = blockIdx.y;
    int n = rb >> 3, lbase = (rb & 7) * 128;
    const u16* wqp = wqkv;
    const u16* wkp = wqkv + 4096;
    const u16* wvp = wqkv + 8192;
    b16x8 wqf[4][2], wkf[4][2], wvf[4][2];
#pragma unroll
    for (int dt = 0; dt < 4; ++dt)
#pragma unroll
        for (int ks = 0; ks < 2; ++ks) {
            int a = (dt * 16 + lr) * 64 + ks * 32 + lg * 8;
            wqf[dt][ks] = *(const b16x8*)&wqp[a];
            wkf[dt][ks] = *(const b16x8*)&wkp[a];
            wvf[dt][ks] = *(const b16x8*)&wvp[a];
        }
#pragma unroll
    for (int rr = 0; rr < 2; ++rr) {
        int rt = w * 2 + rr;
        size_t grow = (size_t)(n * 1024 + lbase + rt * 16 + lr);
        b16x8 aq[2], av[2];
#pragma unroll
        for (int ks = 0; ks < 2; ++ks) {
            aq[ks] = *(const b16x8*)&qbf[grow * D_ + h * 64 + ks * 32 + lg * 8];
            av[ks] = *(const b16x8*)&vbf[grow * D_ + h * 64 + ks * 32 + lg * 8];
        }
#pragma unroll
        for (int dt = 0; dt < 4; ++dt) {
            f32x4 cq = (f32x4){0.f, 0.f, 0.f, 0.f};
            f32x4 ck = (f32x4){0.f, 0.f, 0.f, 0.f};
            f32x4 cv = (f32x4){0.f, 0.f, 0.f, 0.f};
            cq = __builtin_amdgcn_mfma_f32_16x16x32_bf16(aq[0], wqf[dt][0], cq, 0, 0, 0);
            cq = __builtin_amdgcn_mfma_f32_16x16x32_bf16(aq[1], wqf[dt][1], cq, 0, 0, 0);
            ck = __builtin_amdgcn_mfma_f32_16x16x32_bf16(av[0], wkf[dt][0], ck, 0, 0, 0);
            ck = __builtin_amdgcn_mfma_f32_16x16x32_bf16(av[1], wkf[dt][1], ck, 0, 0, 0);
            cv = __builtin_amdgcn_mfma_f32_16x16x32_bf16(wvf[dt][0], av[0], cv, 0, 0, 0);
            cv = __builtin_amdgcn_mfma_f32_16x16x32_bf16(wvf[dt][1], av[1], cv, 0, 0, 0);
#pragma unroll
            for (int r = 0; r < 4; ++r) {
                size_t orow = (size_t)(n * 1024 + lbase + rt * 16 + lg * 4 + r);
                qh[orow * D_ + h * 64 + dt * 16 + lr] = f2bf(cq[r]);
                kh[orow * D_ + h * 64 + dt * 16 + lr] = f2bf(ck[r]);
                vt[((size_t)(n * H_ + h) * 64 + dt * 16 + lg * 4 + r) * L_ + lbase + rt * 16 + lr] = f2bf(cv[r]);
            }
        }
    }
}

// -------- fused MFMA QK^T + softmax + PV: block = 32 q x full L, 8 waves --------
#define PSTR 1032
__global__ __launch_bounds__(512, 4) void qk_pv_kernel(const u16* __restrict__ qh,
                                                       const u16* __restrict__ kh,
                                                       const u16* __restrict__ vt,
                                                       const int* __restrict__ mask,
                                                       float* __restrict__ attn,
                                                       u16* __restrict__ obf) {
    __shared__ u16 P_lds[32 * PSTR];       // 66KB
    __shared__ float redA[32][4];
    __shared__ float redB[32][4];
    int t = threadIdx.x;
    int w = t >> 6, l = t & 63;
    int qsub = w & 1, kq = w >> 1;
    int q0 = blockIdx.x * 32;
    int h = blockIdx.y, n = blockIdx.z;
    int lr = l & 15, lg = l >> 4;

    size_t qrow = ((size_t)(n * L_ + q0 + qsub * 16 + lr) * H_ + h) * HS_;
    b16x8 aq0 = *(const b16x8*)&qh[qrow + lg * 8];
    b16x8 aq1 = *(const b16x8*)&qh[qrow + 32 + lg * 8];

    f32x4 c[16];
#pragma unroll
    for (int i = 0; i < 16; ++i) c[i] = (f32x4){0.f, 0.f, 0.f, 0.f};

    size_t kbase = ((size_t)(n * L_ + kq * 256 + lr) * H_ + h) * HS_ + lg * 8;
#pragma unroll
    for (int kt = 0; kt < 16; ++kt) {
        const u16* kp = &kh[kbase + (size_t)kt * 16 * D_];
        b16x8 bk0 = *(const b16x8*)&kp[0];
        b16x8 bk1 = *(const b16x8*)&kp[32];
        c[kt] = __builtin_amdgcn_mfma_f32_16x16x32_bf16(aq0, bk0, c[kt], 0, 0, 0);
        c[kt] = __builtin_amdgcn_mfma_f32_16x16x32_bf16(aq1, bk1, c[kt], 0, 0, 0);
    }

    const float scl = 0.03125f;   // 1/sqrt(1024)
    int kcol = kq * 256 + lr;
    float rowmax[4] = { -1e30f, -1e30f, -1e30f, -1e30f };
#pragma unroll
    for (int kt = 0; kt < 16; ++kt) {
        int mk = mask[n * L_ + kcol + kt * 16];
#pragma unroll
        for (int r = 0; r < 4; ++r) {
            float s = (mk != 0) ? c[kt][r] * scl : -1e20f;
            c[kt][r] = s;
            rowmax[r] = fmaxf(rowmax[r], s);
        }
    }
#pragma unroll
    for (int o = 8; o > 0; o >>= 1)
#pragma unroll
        for (int r = 0; r < 4; ++r) rowmax[r] = fmaxf(rowmax[r], __shfl_xor(rowmax[r], o));

    int qrow4 = qsub * 16 + lg * 4;
    if (lr == 0) {
#pragma unroll
        for (int r = 0; r < 4; ++r) redA[qrow4 + r][kq] = rowmax[r];
    }
    __syncthreads();
#pragma unroll
    for (int r = 0; r < 4; ++r)
        rowmax[r] = fmaxf(fmaxf(redA[qrow4 + r][0], redA[qrow4 + r][1]),
                          fmaxf(redA[qrow4 + r][2], redA[qrow4 + r][3]));
    float rowsum[4] = { 0.f, 0.f, 0.f, 0.f };
#pragma unroll
    for (int kt = 0; kt < 16; ++kt)
#pragma unroll
        for (int r = 0; r < 4; ++r) {
            float e = __expf(c[kt][r] - rowmax[r]);
            c[kt][r] = e;
            rowsum[r] += e;
        }
#pragma unroll
    for (int o = 8; o > 0; o >>= 1)
#pragma unroll
        for (int r = 0; r < 4; ++r) rowsum[r] += __shfl_xor(rowsum[r], o);
    if (lr == 0) {
#pragma unroll
        for (int r = 0; r < 4; ++r) redB[qrow4 + r][kq] = rowsum[r];
    }
    __syncthreads();
    float inv[4];
#pragma unroll
    for (int r = 0; r < 4; ++r)
        inv[r] = 1.0f / (redB[qrow4 + r][0] + redB[qrow4 + r][1] +
                         redB[qrow4 + r][2] + redB[qrow4 + r][3]);

    // write attn fp32 (mandatory output) + stage P bf16 into LDS
    float* ap = attn + ((size_t)((n * H_ + h) * L_) + q0 + qrow4) * L_ + kcol;
#pragma unroll
    for (int kt = 0; kt < 16; ++kt)
#pragma unroll
        for (int r = 0; r < 4; ++r) {
            float val = c[kt][r] * inv[r];
            ap[(size_t)r * L_ + kt * 16] = val;
            P_lds[(size_t)(qrow4 + r) * PSTR + kcol + kt * 16] = f2bf(val);
        }
    __syncthreads();

    // PV: wave (qsub, dg=kq): O[16q][16d], K=1024
    int dg = kq;
    const u16* vb = vt + ((size_t)(n * H_ + h) * 64 + dg * 16 + lr) * L_;
    const u16* prow = &P_lds[(size_t)(qsub * 16 + lr) * PSTR];
    f32x4 acc = (f32x4){0.f, 0.f, 0.f, 0.f};
#pragma unroll
    for (int ks = 0; ks < 32; ++ks) {
        b16x8 a = *(const b16x8*)&prow[ks * 32 + lg * 8];
        b16x8 b = *(const b16x8*)&vb[ks * 32 + lg * 8];
        acc = __builtin_amdgcn_mfma_f32_16x16x32_bf16(a, b, acc, 0, 0, 0);
    }
#pragma unroll
    for (int r = 0; r < 4; ++r) {
        size_t q = (size_t)(n * L_ + q0 + qsub * 16 + lg * 4 + r);
        obf[q * D_ + h * 64 + dg * 16 + lr] = f2bf(acc[r]);
    }
}

// ---------- bf16 GEMM with fused epilogues, 512 thr / 8 waves / 128x128 tile ----------
// Plain 2D grid (proven r8/r12 config). Double-buffered gl_lds w16, counted vmcnt(4),
// XOR-swizzled LDS. Epilogue side-tensors all bf16:
// MODE 0: v+=bias[col]; (RELU); Cbf=bf16(v)
// MODE 1: col<1024: Cbf=bf16(sig(v)*x) [x=Xbf]; else Zbf=bf16(sig(v-bias[col&1023]))
// MODE 2: z=Zbf; o=(1-z)*Xbf + z*tanh(v); outf=o fp32; (WRH: Cbf=bf16(o))
template<int MODE, int RELU, int WRH>
__global__ __launch_bounds__(512, 4) void gemm_fused_kernel(const u16* __restrict__ A0,
                                                            const u16* __restrict__ A1h,
                                                            const u16* __restrict__ Bw,
                                                            const float* __restrict__ bias,
                                                            const u16* __restrict__ Xbf,
                                                            u16* __restrict__ Zbf,
                                                            u16* __restrict__ Cbf,
                                                            float* __restrict__ outf,
                                                            int K) {
    __shared__ u16 As[2][128 * 64];
    __shared__ u16 Bs[2][128 * 64];
    int t = threadIdx.x, w = t >> 6, l = t & 63;
    int wr = w & 3, wc = w >> 2;
    int m0 = blockIdx.x * 128, n0 = blockIdx.y * 128;
    int fr = l & 15, fq = l >> 4;
    int srow = l >> 3;
    int gc8 = (l & 7) ^ (srow & 7);          // pre-swizzled source col-group (involution)
    const u16* Bbase = Bw + (size_t)n0 * K;

    f32x4 acc[2][4];
#pragma unroll
    for (int i = 0; i < 2; ++i)
#pragma unroll
        for (int j = 0; j < 4; ++j) acc[i][j] = (f32x4){0.f, 0.f, 0.f, 0.f};

    auto STAGE = [&](int buf, int kk) {
        const u16* Asrc = (MODE == 0 || kk < 1024) ? A0 : A1h;
        int kc = kk & 1023;
#pragma unroll
        for (int i = 0; i < 2; ++i) {
            int r0 = (i * 8 + w) * 8;            // wave-uniform 8-row group
            gl_lds16(&Asrc[(size_t)(m0 + r0 + srow) * 1024 + kc + gc8 * 8], &As[buf][r0 * 64]);
            gl_lds16(&Bbase[(size_t)(r0 + srow) * K + kk + gc8 * 8], &Bs[buf][r0 * 64]);
        }
    };
    STAGE(0, 0);
    const int NT = K >> 6;
    for (int kt = 0; kt < NT; ++kt) {
        int cur = kt & 1;
        if (kt + 1 < NT) {
            STAGE(cur ^ 1, (kt + 1) << 6);
            asm volatile("s_waitcnt vmcnt(4)" ::: "memory");
        } else {
            asm volatile("s_waitcnt vmcnt(0)" ::: "memory");
        }
        __builtin_amdgcn_s_barrier();
#pragma unroll
        for (int ks = 0; ks < 2; ++ks) {
            b16x8 af[2], bf[4];
#pragma unroll
            for (int i = 0; i < 2; ++i) {
                int row = wr * 32 + i * 16 + fr;
                af[i] = *(const b16x8*)&As[cur][row * 64 + (((ks * 4 + fq) ^ (fr & 7)) * 8)];
            }
#pragma unroll
            for (int j = 0; j < 4; ++j) {
                int row = wc * 64 + j * 16 + fr;
                bf[j] = *(const b16x8*)&Bs[cur][row * 64 + (((ks * 4 + fq) ^ (fr & 7)) * 8)];
            }
#pragma unroll
            for (int i = 0; i < 2; ++i)
#pragma unroll
                for (int j = 0; j < 4; ++j)
                    acc[i][j] = __builtin_amdgcn_mfma_f32_16x16x32_bf16(af[i], bf[j], acc[i][j], 0, 0, 0);
        }
        asm volatile("s_waitcnt lgkmcnt(0)" ::: "memory");
        __builtin_amdgcn_s_barrier();
    }

#pragma unroll
    for (int i = 0; i < 2; ++i) {
#pragma unroll
        for (int j = 0; j < 4; ++j) {
            int row = m0 + wr * 32 + i * 16 + fq * 4;
            int col = n0 + wc * 64 + j * 16 + fr;
            int c1 = col & 1023;
#pragma unroll
            for (int r = 0; r < 4; ++r) {
                float v = acc[i][j][r];
                size_t off = (size_t)(row + r) * 1024 + c1;
                if (MODE == 0) {
                    v += bias[col];
                    if (RELU) v = fmaxf(v, 0.f);
                    Cbf[off] = f2bf(v);
                } else if (MODE == 1) {
                    if (col < 1024) Cbf[off] = f2bf(sigmoidf_(v) * bf2f(Xbf[off]));
                    else            Zbf[off] = f2bf(sigmoidf_(v - bias[c1]));
                } else {
                    float z = bf2f(Zbf[off]);
                    float o = (1.f - z) * bf2f(Xbf[off]) + z * tanhf(v);
                    outf[off] = o;
                    if (WRH) Cbf[off] = f2bf(o);
                }
            }
        }
    }
}

// ---------- bf16 GEMM 256x128 tile, MODE-1 epilogue (rz gates), 512 thr / 8 waves ----------
// For M=4096 x N=2048 x K=2048: grid 16x16 = 256 blocks (1/CU). 32 MFMA per barrier-pair
// (2x amortization vs 128^2) and AI 85 FLOP/B (vs 64). LDS 96KB. Wave = 64x64 tile
// (wr=w&3 row-quarter, wc=w>>2 col-half), acc 4x4. 6 loads/thread/stage -> vmcnt(6).
// Same proven dbuf + XOR-swizzle + 2-barrier structure (parameter change only).
__global__ __launch_bounds__(512, 2) void gemm_big_rz_kernel(const u16* __restrict__ A0,
                                                             const u16* __restrict__ A1h,
                                                             const u16* __restrict__ Bw,
                                                             const float* __restrict__ bias,
                                                             const u16* __restrict__ Xbf,
                                                             u16* __restrict__ Zbf,
                                                             u16* __restrict__ Cbf,
                                                             int K) {
    __shared__ u16 As[2][256 * 64];
    __shared__ u16 Bs[2][128 * 64];
    int t = threadIdx.x, w = t >> 6, l = t & 63;
    int wr = w & 3, wc = w >> 2;
    int m0 = blockIdx.x * 256, n0 = blockIdx.y * 128;
    int fr = l & 15, fq = l >> 4;
    int srow = l >> 3;
    int gc8 = (l & 7) ^ (srow & 7);          // pre-swizzled source col-group (involution)
    const u16* Bbase = Bw + (size_t)n0 * K;

    f32x4 acc[4][4];
#pragma unroll
    for (int i = 0; i < 4; ++i)
#pragma unroll
        for (int j = 0; j < 4; ++j) acc[i][j] = (f32x4){0.f, 0.f, 0.f, 0.f};

    auto STAGE = [&](int buf, int kk) {
        const u16* Asrc = (kk < 1024) ? A0 : A1h;
        int kc = kk & 1023;
#pragma unroll
        for (int i = 0; i < 4; ++i) {
            int r0 = (i * 8 + w) * 8;            // wave-uniform 8-row group (32 groups = 256 rows)
            gl_lds16(&Asrc[(size_t)(m0 + r0 + srow) * 1024 + kc + gc8 * 8], &As[buf][r0 * 64]);
        }
#pragma unroll
        for (int j = 0; j < 2; ++j) {
            int r0 = (j * 8 + w) * 8;            // 16 groups = 128 rows
            gl_lds16(&Bbase[(size_t)(r0 + srow) * K + kk + gc8 * 8], &Bs[buf][r0 * 64]);
        }
    };
    STAGE(0, 0);
    const int NT = K >> 6;
    for (int kt = 0; kt < NT; ++kt) {
        int cur = kt & 1;
        if (kt + 1 < NT) {
            STAGE(cur ^ 1, (kt + 1) << 6);
            asm volatile("s_waitcnt vmcnt(6)" ::: "memory");
        } else {
            asm volatile("s_waitcnt vmcnt(0)" ::: "memory");
        }
        __builtin_amdgcn_s_barrier();
#pragma unroll
        for (int ks = 0; ks < 2; ++ks) {
            b16x8 af[4], bf[4];
#pragma unroll
            for (int i = 0; i < 4; ++i) {
                int row = wr * 64 + i * 16 + fr;
                af[i] = *(const b16x8*)&As[cur][row * 64 + (((ks * 4 + fq) ^ (fr & 7)) * 8)];
            }
#pragma unroll
            for (int j = 0; j < 4; ++j) {
                int row = wc * 64 + j * 16 + fr;
                bf[j] = *(const b16x8*)&Bs[cur][row * 64 + (((ks * 4 + fq) ^ (fr & 7)) * 8)];
            }
#pragma unroll
            for (int i = 0; i < 4; ++i)
#pragma unroll
                for (int j = 0; j < 4; ++j)
                    acc[i][j] = __builtin_amdgcn_mfma_f32_16x16x32_bf16(af[i], bf[j], acc[i][j], 0, 0, 0);
        }
        asm volatile("s_waitcnt lgkmcnt(0)" ::: "memory");
        __builtin_amdgcn_s_barrier();
    }

#pragma unroll
    for (int i = 0; i < 4; ++i) {
#pragma unroll
        for (int j = 0; j < 4; ++j) {
            int row = m0 + wr * 64 + i * 16 + fq * 4;
            int col = n0 + wc * 64 + j * 16 + fr;
            int c1 = col & 1023;
#pragma unroll
            for (int r = 0; r < 4; ++r) {
                float v = acc[i][j][r];
                size_t off = (size_t)(row + r) * 1024 + c1;
                if (col < 1024) Cbf[off] = f2bf(sigmoidf_(v) * bf2f(Xbf[off]));
                else            Zbf[off] = f2bf(sigmoidf_(v - bias[c1]));
            }
        }
    }
}

extern "C" void kernel_launch(void* const* d_in, const int* in_sizes, int n_in,
                              void* d_out, int out_size, void* d_ws, size_t ws_size,
                              hipStream_t stream) {
    const float* value = (const float*)d_in[0];
    // d_in[1] = key (unused: reference sets k_ = normed value)
    const float* query = (const float*)d_in[2];
    const int* mask = (const int*)d_in[3];
    const float* wq = (const float*)d_in[4];
    const float* wk = (const float*)d_in[5];
    const float* wv = (const float*)d_in[6];
    const float* w_out = (const float*)d_in[7];
    const float* b_out = (const float*)d_in[8];
    const float* fc_w = (const float*)d_in[9];
    const float* fc_b = (const float*)d_in[10];
    const float* ln1_s = (const float*)d_in[11];
    const float* ln1_b = (const float*)d_in[12];
    const float* lnkv_s = (const float*)d_in[13];
    const float* lnkv_b = (const float*)d_in[14];
    const float* ln2_s = (const float*)d_in[15];
    const float* ln2_b = (const float*)d_in[16];
    const float* g1_W = (const float*)d_in[17];
    const float* g1_U = (const float*)d_in[18];
    const float* g1_bg = (const float*)d_in[19];
    const float* g2_W = (const float*)d_in[20];
    const float* g2_U = (const float*)d_in[21];
    const float* g2_bg = (const float*)d_in[22];

    float* out_f = (float*)d_out;                     // final out [4096][1024] fp32
    float* attn_f = out_f + MD_;                      // attn [N,H,L,L] fp32 (output 1)
    float* OutH = out_f;                              // h lives in out slice; h2 writes in place

    // ---- d_ws layout (u16 units) ----
    u16* WS = (u16*)d_ws;
    u16* Wop = WS;                                    // DD
    u16* Wfc = WS + (size_t)DD_;                      // DD
    u16* WQKV = WS + 2 * (size_t)DD_;                 // 16384
    u16* G1rz = WQKV + 16384;                         // 4DD
    u16* G1h  = G1rz + 4 * (size_t)DD_;               // 2DD
    u16* G2rz = G1h + 2 * (size_t)DD_;                // 4DD
    u16* G2h  = G2rz + 4 * (size_t)DD_;               // 2DD
    u16* Y    = G2h + 2 * (size_t)DD_;                // o_proj out
    u16* Xq   = Y + MD_;                              // query bf16
    u16* T1   = Xq + MD_;                             // t gate1 / reused t gate2
    u16* Hb   = T1 + MD_;                             // h bf16
    u16* F    = Hb + MD_;                             // fc out
    u16* QH   = F + MD_;
    u16* KH   = QH + MD_;
    u16* VT   = KH + MD_;
    u16* OBF  = VT + MD_;
    u16* LNQ  = OBF + MD_;
    u16* LNV  = LNQ + MD_;
    u16* LN2  = LNV + MD_;
    u16* Zb   = LN2 + MD_;                            // z bf16 [4096][1024]

    dim3 grid_n1024(M_ / 128, 8);                     // 256 blocks
    dim3 grid_big(M_ / 256, 16);                      // 16 x 16 = 256 blocks (256x128 tiles)

    // ---- weight prep + query cvt (1 launch) ----
    prep_weights_kernel<<<9222, 256, 0, stream>>>(w_out, fc_w, wq, wk, wv,
                                                  g1_W, g1_U, g2_W, g2_U, query, Xq, WS);

    // ---- attention ----
    ln2in1_kernel<<<dim3(M_, 2), 256, 0, stream>>>(query, LNQ, ln1_s, ln1_b,
                                                   value, LNV, lnkv_s, lnkv_b);
    proj_mfma_kernel<<<dim3(32, 16), 256, 0, stream>>>(LNQ, LNV, WQKV, QH, KH, VT);
    qk_pv_kernel<<<dim3(L_ / 32, H_, N_), 512, 0, stream>>>(QH, KH, VT, mask, attn_f, OBF);
    // o_proj -> Y
    gemm_fused_kernel<0, 0, 0><<<grid_n1024, 512, 0, stream>>>(OBF, nullptr, Wop, b_out,
                                                               nullptr, nullptr, Y, nullptr, 1024);
    // GRU gate 1 (x = query -> Xq): big-tile rz
    gemm_big_rz_kernel<<<grid_big, 512, 0, stream>>>(Y, Xq, G1rz, g1_bg, Xq, Zb, T1, 2048);
    gemm_fused_kernel<2, 0, 1><<<grid_n1024, 512, 0, stream>>>(Y, T1, G1h, nullptr,
                                                               Xq, Zb, Hb, OutH, 2048);
    // LN2 + FC
    ln_kernel<<<M_, 256, 0, stream>>>(OutH, LN2, ln2_s, ln2_b);
    gemm_fused_kernel<0, 1, 0><<<grid_n1024, 512, 0, stream>>>(LN2, nullptr, Wfc, fc_b,
                                                               nullptr, nullptr, F, nullptr, 1024);
    // GRU gate 2 (x = h -> Hb): big-tile rz
    gemm_big_rz_kernel<<<grid_big, 512, 0, stream>>>(F, Hb, G2rz, g2_bg, Hb, Zb, T1, 2048);
    gemm_fused_kernel<2, 0, 0><<<grid_n1024, 512, 0, stream>>>(F, T1, G2h, nullptr,
                                                               Hb, Zb, nullptr, out_f, 2048);
}

// Round 16
// 386.295 us; speedup vs baseline: 1.0322x; 1.0322x over previous
//
#include <hip/hip_runtime.h>
#include <cstdint>
#include <cstddef>

#define N_ 4
#define L_ 1024
#define D_ 1024
#define H_ 16
#define HS_ 64
#define M_ (N_*L_)       // 4096 rows
#define DD_ (D_*D_)      // 1048576
#define MD_ ((size_t)M_*D_)

typedef unsigned short u16;
typedef __bf16 b16x8 __attribute__((ext_vector_type(8)));
typedef float f32x4 __attribute__((ext_vector_type(4)));

__device__ __forceinline__ float sigmoidf_(float x) { return 1.0f / (1.0f + __expf(-x)); }
__device__ __forceinline__ u16 f2bf(float f) {
    union { float f; uint32_t u; } c; c.f = f;
    uint32_t u = c.u;
    u += 0x7fffu + ((u >> 16) & 1u);   // RNE
    return (u16)(u >> 16);
}
__device__ __forceinline__ float bf2f(u16 u) {
    union { uint32_t u; float f; } c; c.u = ((uint32_t)u) << 16; return c.f;
}

// async global->LDS, 16B per lane
__device__ __forceinline__ void gl_lds16(const void* g, void* l) {
    auto gp = reinterpret_cast<const __attribute__((address_space(1))) unsigned int*>(
        reinterpret_cast<uintptr_t>(g));
    auto lp = reinterpret_cast<__attribute__((address_space(3))) unsigned int*>(
        reinterpret_cast<uintptr_t>(l));
    __builtin_amdgcn_global_load_lds(gp, lp, 16, 0, 0);
}

// ---------------- one-shot weight prep + query cvt: all bf16 ----------------
// ws0 layout (u16): Wop[DD] Wfc[DD] WQKV[16384] G1rz[4DD] G1h[2DD] G2rz[4DD] G2h[2DD]
__global__ __launch_bounds__(256) void prep_weights_kernel(
    const float* __restrict__ w_out, const float* __restrict__ fc_w,
    const float* __restrict__ wq, const float* __restrict__ wk, const float* __restrict__ wv,
    const float* __restrict__ g1W, const float* __restrict__ g1U,
    const float* __restrict__ g2W, const float* __restrict__ g2U,
    const float* __restrict__ query, u16* __restrict__ Xq,
    u16* __restrict__ ws0) {
    u16* Wop = ws0;
    u16* Wfc = ws0 + (size_t)DD_;
    u16* WQKV = ws0 + 2 * (size_t)DD_;
    u16* G1rz = WQKV + 16384;
    u16* G1h = G1rz + 4 * (size_t)DD_;
    u16* G2rz = G1h + 2 * (size_t)DD_;
    u16* G2h = G2rz + 4 * (size_t)DD_;
    int b = blockIdx.x, t = threadIdx.x;
    const float* src; u16* dst; size_t si, di;
    if (b < 512) {
        size_t f = (size_t)b * 2048 + t * 8; src = w_out; si = f; dst = Wop; di = f;
    } else if (b < 1024) {
        size_t f = (size_t)(b - 512) * 2048 + t * 8; src = fc_w; si = f; dst = Wfc; di = f;
    } else if (b < 1030) {
        size_t f = (size_t)(b - 1024) * 2048 + t * 8;
        int which = (int)(f >> 12); size_t off = f & 4095;
        src = which == 0 ? wq : (which == 1 ? wk : wv); si = off; dst = WQKV; di = f;
    } else if (b < 3078) {
        size_t f = (size_t)(b - 1030) * 2048 + t * 8;
        size_t row = f >> 11, k = f & 2047; size_t n2 = (row >= 1024) ? 1 : 0;
        src = (k < 1024) ? (g1W + n2 * DD_) : (g1U + n2 * DD_);
        si = (row & 1023) * 1024 + (k & 1023); dst = G1rz; di = f;
    } else if (b < 4102) {
        size_t f = (size_t)(b - 3078) * 2048 + t * 8;
        size_t row = f >> 11, k = f & 2047;
        src = (k < 1024) ? (g1W + 2 * (size_t)DD_) : (g1U + 2 * (size_t)DD_);
        si = row * 1024 + (k & 1023); dst = G1h; di = f;
    } else if (b < 6150) {
        size_t f = (size_t)(b - 4102) * 2048 + t * 8;
        size_t row = f >> 11, k = f & 2047; size_t n2 = (row >= 1024) ? 1 : 0;
        src = (k < 1024) ? (g2W + n2 * DD_) : (g2U + n2 * DD_);
        si = (row & 1023) * 1024 + (k & 1023); dst = G2rz; di = f;
    } else if (b < 7174) {
        size_t f = (size_t)(b - 6150) * 2048 + t * 8;
        size_t row = f >> 11, k = f & 2047;
        src = (k < 1024) ? (g2W + 2 * (size_t)DD_) : (g2U + 2 * (size_t)DD_);
        si = row * 1024 + (k & 1023); dst = G2h; di = f;
    } else {
        size_t f = (size_t)(b - 7174) * 2048 + t * 8;
        src = query; si = f; dst = Xq; di = f;
    }
    float4 a = *(const float4*)&src[si];
    float4 b4 = *(const float4*)&src[si + 4];
    u16 o[8] = { f2bf(a.x), f2bf(a.y), f2bf(a.z), f2bf(a.w),
                 f2bf(b4.x), f2bf(b4.y), f2bf(b4.z), f2bf(b4.w) };
    *(uint4*)&dst[di] = *(uint4*)o;
}

// ---------------- LayerNorm -> bf16 (blockIdx.y selects stream 0/1) ----------------
__global__ __launch_bounds__(256) void ln2in1_kernel(const float* __restrict__ x0, u16* __restrict__ y0,
                                                     const float* __restrict__ sc0, const float* __restrict__ bi0,
                                                     const float* __restrict__ x1, u16* __restrict__ y1,
                                                     const float* __restrict__ sc1, const float* __restrict__ bi1) {
    int row = blockIdx.x;
    const float* x = blockIdx.y ? x1 : x0;
    u16* y = blockIdx.y ? y1 : y0;
    const float* sc = blockIdx.y ? sc1 : sc0;
    const float* bi = blockIdx.y ? bi1 : bi0;
    const float* xr = x + (size_t)row * D_;
    int t = threadIdx.x;
    float4 v = *(const float4*)&xr[t * 4];
    float s = v.x + v.y + v.z + v.w;
    float q = v.x * v.x + v.y * v.y + v.z * v.z + v.w * v.w;
#pragma unroll
    for (int o = 32; o > 0; o >>= 1) { s += __shfl_xor(s, o); q += __shfl_xor(q, o); }
    __shared__ float ss[4], sq[4];
    int w = t >> 6;
    if ((t & 63) == 0) { ss[w] = s; sq[w] = q; }
    __syncthreads();
    s = ss[0] + ss[1] + ss[2] + ss[3];
    q = sq[0] + sq[1] + sq[2] + sq[3];
    float mean = s * (1.0f / D_);
    float var = q * (1.0f / D_) - mean * mean;
    float inv = rsqrtf(var + 1e-5f);
    float4 sv = *(const float4*)&sc[t * 4];
    float4 bv = *(const float4*)&bi[t * 4];
    u16 ov[4] = { f2bf((v.x - mean) * inv * sv.x + bv.x),
                  f2bf((v.y - mean) * inv * sv.y + bv.y),
                  f2bf((v.z - mean) * inv * sv.z + bv.z),
                  f2bf((v.w - mean) * inv * sv.w + bv.w) };
    *(ushort4*)&y[(size_t)row * D_ + t * 4] = *(ushort4*)ov;
}

// ---------------- single LayerNorm -> bf16 (ln2) ----------------
__global__ __launch_bounds__(256) void ln_kernel(const float* __restrict__ x, u16* __restrict__ y,
                                                 const float* __restrict__ sc, const float* __restrict__ bi) {
    int row = blockIdx.x;
    const float* xr = x + (size_t)row * D_;
    int t = threadIdx.x;
    float4 v = *(const float4*)&xr[t * 4];
    float s = v.x + v.y + v.z + v.w;
    float q = v.x * v.x + v.y * v.y + v.z * v.z + v.w * v.w;
#pragma unroll
    for (int o = 32; o > 0; o >>= 1) { s += __shfl_xor(s, o); q += __shfl_xor(q, o); }
    __shared__ float ss[4], sq[4];
    int w = t >> 6;
    if ((t & 63) == 0) { ss[w] = s; sq[w] = q; }
    __syncthreads();
    s = ss[0] + ss[1] + ss[2] + ss[3];
    q = sq[0] + sq[1] + sq[2] + sq[3];
    float mean = s * (1.0f / D_);
    float var = q * (1.0f / D_) - mean * mean;
    float inv = rsqrtf(var + 1e-5f);
    float4 sv = *(const float4*)&sc[t * 4];
    float4 bv = *(const float4*)&bi[t * 4];
    u16 ov[4] = { f2bf((v.x - mean) * inv * sv.x + bv.x),
                  f2bf((v.y - mean) * inv * sv.y + bv.y),
                  f2bf((v.z - mean) * inv * sv.z + bv.z),
                  f2bf((v.w - mean) * inv * sv.w + bv.w) };
    *(ushort4*)&y[(size_t)row * D_ + t * 4] = *(ushort4*)ov;
}

// -------- MFMA per-head projections: qh/kh row-major + vt transposed, all bf16 --------
__global__ __launch_bounds__(256) void proj_mfma_kernel(const u16* __restrict__ qbf,
                                                        const u16* __restrict__ vbf,
                                                        const u16* __restrict__ wqkv,
                                                        u16* __restrict__ qh, u16* __restrict__ kh,
                                                        u16* __restrict__ vt) {
    int t = threadIdx.x, w = t >> 6, l = t & 63;
    int lr = l & 15, lg = l >> 4;
    int rb = blockIdx.x, h = blockIdx.y;
    int n = rb >> 3, lbase = (rb & 7) * 128;
    const u16* wqp = wqkv;
    const u16* wkp = wqkv + 4096;
    const u16* wvp = wqkv + 8192;
    b16x8 wqf[4][2], wkf[4][2], wvf[4][2];
#pragma unroll
    for (int dt = 0; dt < 4; ++dt)
#pragma unroll
        for (int ks = 0; ks < 2; ++ks) {
            int a = (dt * 16 + lr) * 64 + ks * 32 + lg * 8;
            wqf[dt][ks] = *(const b16x8*)&wqp[a];
            wkf[dt][ks] = *(const b16x8*)&wkp[a];
            wvf[dt][ks] = *(const b16x8*)&wvp[a];
        }
#pragma unroll
    for (int rr = 0; rr < 2; ++rr) {
        int rt = w * 2 + rr;
        size_t grow = (size_t)(n * 1024 + lbase + rt * 16 + lr);
        b16x8 aq[2], av[2];
#pragma unroll
        for (int ks = 0; ks < 2; ++ks) {
            aq[ks] = *(const b16x8*)&qbf[grow * D_ + h * 64 + ks * 32 + lg * 8];
            av[ks] = *(const b16x8*)&vbf[grow * D_ + h * 64 + ks * 32 + lg * 8];
        }
#pragma unroll
        for (int dt = 0; dt < 4; ++dt) {
            f32x4 cq = (f32x4){0.f, 0.f, 0.f, 0.f};
            f32x4 ck = (f32x4){0.f, 0.f, 0.f, 0.f};
            f32x4 cv = (f32x4){0.f, 0.f, 0.f, 0.f};
            cq = __builtin_amdgcn_mfma_f32_16x16x32_bf16(aq[0], wqf[dt][0], cq, 0, 0, 0);
            cq = __builtin_amdgcn_mfma_f32_16x16x32_bf16(aq[1], wqf[dt][1], cq, 0, 0, 0);
            ck = __builtin_amdgcn_mfma_f32_16x16x32_bf16(av[0], wkf[dt][0], ck, 0, 0, 0);
            ck = __builtin_amdgcn_mfma_f32_16x16x32_bf16(av[1], wkf[dt][1], ck, 0, 0, 0);
            cv = __builtin_amdgcn_mfma_f32_16x16x32_bf16(wvf[dt][0], av[0], cv, 0, 0, 0);
            cv = __builtin_amdgcn_mfma_f32_16x16x32_bf16(wvf[dt][1], av[1], cv, 0, 0, 0);
#pragma unroll
            for (int r = 0; r < 4; ++r) {
                size_t orow = (size_t)(n * 1024 + lbase + rt * 16 + lg * 4 + r);
                qh[orow * D_ + h * 64 + dt * 16 + lr] = f2bf(cq[r]);
                kh[orow * D_ + h * 64 + dt * 16 + lr] = f2bf(ck[r]);
                vt[((size_t)(n * H_ + h) * 64 + dt * 16 + lg * 4 + r) * L_ + lbase + rt * 16 + lr] = f2bf(cv[r]);
            }
        }
    }
}

// -------- fused MFMA QK^T + softmax + PV: block = 32 q x full L, 8 waves --------
#define PSTR 1032
__global__ __launch_bounds__(512, 4) void qk_pv_kernel(const u16* __restrict__ qh,
                                                       const u16* __restrict__ kh,
                                                       const u16* __restrict__ vt,
                                                       const int* __restrict__ mask,
                                                       float* __restrict__ attn,
                                                       u16* __restrict__ obf) {
    __shared__ u16 P_lds[32 * PSTR];       // 66KB
    __shared__ float redA[32][4];
    __shared__ float redB[32][4];
    int t = threadIdx.x;
    int w = t >> 6, l = t & 63;
    int qsub = w & 1, kq = w >> 1;
    int q0 = blockIdx.x * 32;
    int h = blockIdx.y, n = blockIdx.z;
    int lr = l & 15, lg = l >> 4;

    size_t qrow = ((size_t)(n * L_ + q0 + qsub * 16 + lr) * H_ + h) * HS_;
    b16x8 aq0 = *(const b16x8*)&qh[qrow + lg * 8];
    b16x8 aq1 = *(const b16x8*)&qh[qrow + 32 + lg * 8];

    f32x4 c[16];
#pragma unroll
    for (int i = 0; i < 16; ++i) c[i] = (f32x4){0.f, 0.f, 0.f, 0.f};

    size_t kbase = ((size_t)(n * L_ + kq * 256 + lr) * H_ + h) * HS_ + lg * 8;
#pragma unroll
    for (int kt = 0; kt < 16; ++kt) {
        const u16* kp = &kh[kbase + (size_t)kt * 16 * D_];
        b16x8 bk0 = *(const b16x8*)&kp[0];
        b16x8 bk1 = *(const b16x8*)&kp[32];
        c[kt] = __builtin_amdgcn_mfma_f32_16x16x32_bf16(aq0, bk0, c[kt], 0, 0, 0);
        c[kt] = __builtin_amdgcn_mfma_f32_16x16x32_bf16(aq1, bk1, c[kt], 0, 0, 0);
    }

    const float scl = 0.03125f;   // 1/sqrt(1024)
    int kcol = kq * 256 + lr;
    float rowmax[4] = { -1e30f, -1e30f, -1e30f, -1e30f };
#pragma unroll
    for (int kt = 0; kt < 16; ++kt) {
        int mk = mask[n * L_ + kcol + kt * 16];
#pragma unroll
        for (int r = 0; r < 4; ++r) {
            float s = (mk != 0) ? c[kt][r] * scl : -1e20f;
            c[kt][r] = s;
            rowmax[r] = fmaxf(rowmax[r], s);
        }
    }
#pragma unroll
    for (int o = 8; o > 0; o >>= 1)
#pragma unroll
        for (int r = 0; r < 4; ++r) rowmax[r] = fmaxf(rowmax[r], __shfl_xor(rowmax[r], o));

    int qrow4 = qsub * 16 + lg * 4;
    if (lr == 0) {
#pragma unroll
        for (int r = 0; r < 4; ++r) redA[qrow4 + r][kq] = rowmax[r];
    }
    __syncthreads();
#pragma unroll
    for (int r = 0; r < 4; ++r)
        rowmax[r] = fmaxf(fmaxf(redA[qrow4 + r][0], redA[qrow4 + r][1]),
                          fmaxf(redA[qrow4 + r][2], redA[qrow4 + r][3]));
    float rowsum[4] = { 0.f, 0.f, 0.f, 0.f };
#pragma unroll
    for (int kt = 0; kt < 16; ++kt)
#pragma unroll
        for (int r = 0; r < 4; ++r) {
            float e = __expf(c[kt][r] - rowmax[r]);
            c[kt][r] = e;
            rowsum[r] += e;
        }
#pragma unroll
    for (int o = 8; o > 0; o >>= 1)
#pragma unroll
        for (int r = 0; r < 4; ++r) rowsum[r] += __shfl_xor(rowsum[r], o);
    if (lr == 0) {
#pragma unroll
        for (int r = 0; r < 4; ++r) redB[qrow4 + r][kq] = rowsum[r];
    }
    __syncthreads();
    float inv[4];
#pragma unroll
    for (int r = 0; r < 4; ++r)
        inv[r] = 1.0f / (redB[qrow4 + r][0] + redB[qrow4 + r][1] +
                         redB[qrow4 + r][2] + redB[qrow4 + r][3]);

    // write attn fp32 (mandatory output) + stage P bf16 into LDS
    float* ap = attn + ((size_t)((n * H_ + h) * L_) + q0 + qrow4) * L_ + kcol;
#pragma unroll
    for (int kt = 0; kt < 16; ++kt)
#pragma unroll
        for (int r = 0; r < 4; ++r) {
            float val = c[kt][r] * inv[r];
            ap[(size_t)r * L_ + kt * 16] = val;
            P_lds[(size_t)(qrow4 + r) * PSTR + kcol + kt * 16] = f2bf(val);
        }
    __syncthreads();

    // PV: wave (qsub, dg=kq): O[16q][16d], K=1024
    int dg = kq;
    const u16* vb = vt + ((size_t)(n * H_ + h) * 64 + dg * 16 + lr) * L_;
    const u16* prow = &P_lds[(size_t)(qsub * 16 + lr) * PSTR];
    f32x4 acc = (f32x4){0.f, 0.f, 0.f, 0.f};
#pragma unroll
    for (int ks = 0; ks < 32; ++ks) {
        b16x8 a = *(const b16x8*)&prow[ks * 32 + lg * 8];
        b16x8 b = *(const b16x8*)&vb[ks * 32 + lg * 8];
        acc = __builtin_amdgcn_mfma_f32_16x16x32_bf16(a, b, acc, 0, 0, 0);
    }
#pragma unroll
    for (int r = 0; r < 4; ++r) {
        size_t q = (size_t)(n * L_ + q0 + qsub * 16 + lg * 4 + r);
        obf[q * D_ + h * 64 + dg * 16 + lr] = f2bf(acc[r]);
    }
}

// ---------- bf16 GEMM with fused epilogues, 512 thr / 8 waves / 128x128 tile ----------
// Plain 2D grid (proven r8/r12 config). Double-buffered gl_lds w16, counted vmcnt(4),
// XOR-swizzled LDS. Epilogue side-tensors all bf16:
// MODE 0: v+=bias[col]; (RELU); Cbf=bf16(v)
// MODE 1: col<1024: Cbf=bf16(sig(v)*x) [x=Xbf]; else Zbf=bf16(sig(v-bias[col&1023]))
// MODE 2: z=Zbf; o=(1-z)*Xbf + z*tanh(v); outf=o fp32; (WRH: Cbf=bf16(o))
template<int MODE, int RELU, int WRH>
__global__ __launch_bounds__(512, 4) void gemm_fused_kernel(const u16* __restrict__ A0,
                                                            const u16* __restrict__ A1h,
                                                            const u16* __restrict__ Bw,
                                                            const float* __restrict__ bias,
                                                            const u16* __restrict__ Xbf,
                                                            u16* __restrict__ Zbf,
                                                            u16* __restrict__ Cbf,
                                                            float* __restrict__ outf,
                                                            int K) {
    __shared__ u16 As[2][128 * 64];
    __shared__ u16 Bs[2][128 * 64];
    int t = threadIdx.x, w = t >> 6, l = t & 63;
    int wr = w & 3, wc = w >> 2;
    int m0 = blockIdx.x * 128, n0 = blockIdx.y * 128;
    int fr = l & 15, fq = l >> 4;
    int srow = l >> 3;
    int gc8 = (l & 7) ^ (srow & 7);          // pre-swizzled source col-group (involution)
    const u16* Bbase = Bw + (size_t)n0 * K;

    f32x4 acc[2][4];
#pragma unroll
    for (int i = 0; i < 2; ++i)
#pragma unroll
        for (int j = 0; j < 4; ++j) acc[i][j] = (f32x4){0.f, 0.f, 0.f, 0.f};

    auto STAGE = [&](int buf, int kk) {
        const u16* Asrc = (MODE == 0 || kk < 1024) ? A0 : A1h;
        int kc = kk & 1023;
#pragma unroll
        for (int i = 0; i < 2; ++i) {
            int r0 = (i * 8 + w) * 8;            // wave-uniform 8-row group
            gl_lds16(&Asrc[(size_t)(m0 + r0 + srow) * 1024 + kc + gc8 * 8], &As[buf][r0 * 64]);
            gl_lds16(&Bbase[(size_t)(r0 + srow) * K + kk + gc8 * 8], &Bs[buf][r0 * 64]);
        }
    };
    STAGE(0, 0);
    const int NT = K >> 6;
    for (int kt = 0; kt < NT; ++kt) {
        int cur = kt & 1;
        if (kt + 1 < NT) {
            STAGE(cur ^ 1, (kt + 1) << 6);
            asm volatile("s_waitcnt vmcnt(4)" ::: "memory");
        } else {
            asm volatile("s_waitcnt vmcnt(0)" ::: "memory");
        }
        __builtin_amdgcn_s_barrier();
#pragma unroll
        for (int ks = 0; ks < 2; ++ks) {
            b16x8 af[2], bf[4];
#pragma unroll
            for (int i = 0; i < 2; ++i) {
                int row = wr * 32 + i * 16 + fr;
                af[i] = *(const b16x8*)&As[cur][row * 64 + (((ks * 4 + fq) ^ (fr & 7)) * 8)];
            }
#pragma unroll
            for (int j = 0; j < 4; ++j) {
                int row = wc * 64 + j * 16 + fr;
                bf[j] = *(const b16x8*)&Bs[cur][row * 64 + (((ks * 4 + fq) ^ (fr & 7)) * 8)];
            }
#pragma unroll
            for (int i = 0; i < 2; ++i)
#pragma unroll
                for (int j = 0; j < 4; ++j)
                    acc[i][j] = __builtin_amdgcn_mfma_f32_16x16x32_bf16(af[i], bf[j], acc[i][j], 0, 0, 0);
        }
        asm volatile("s_waitcnt lgkmcnt(0)" ::: "memory");
        __builtin_amdgcn_s_barrier();
    }

#pragma unroll
    for (int i = 0; i < 2; ++i) {
#pragma unroll
        for (int j = 0; j < 4; ++j) {
            int row = m0 + wr * 32 + i * 16 + fq * 4;
            int col = n0 + wc * 64 + j * 16 + fr;
            int c1 = col & 1023;
#pragma unroll
            for (int r = 0; r < 4; ++r) {
                float v = acc[i][j][r];
                size_t off = (size_t)(row + r) * 1024 + c1;
                if (MODE == 0) {
                    v += bias[col];
                    if (RELU) v = fmaxf(v, 0.f);
                    Cbf[off] = f2bf(v);
                } else if (MODE == 1) {
                    if (col < 1024) Cbf[off] = f2bf(sigmoidf_(v) * bf2f(Xbf[off]));
                    else            Zbf[off] = f2bf(sigmoidf_(v - bias[c1]));
                } else {
                    float z = bf2f(Zbf[off]);
                    float o = (1.f - z) * bf2f(Xbf[off]) + z * tanhf(v);
                    outf[off] = o;
                    if (WRH) Cbf[off] = f2bf(o);
                }
            }
        }
    }
}

extern "C" void kernel_launch(void* const* d_in, const int* in_sizes, int n_in,
                              void* d_out, int out_size, void* d_ws, size_t ws_size,
                              hipStream_t stream) {
    const float* value = (const float*)d_in[0];
    // d_in[1] = key (unused: reference sets k_ = normed value)
    const float* query = (const float*)d_in[2];
    const int* mask = (const int*)d_in[3];
    const float* wq = (const float*)d_in[4];
    const float* wk = (const float*)d_in[5];
    const float* wv = (const float*)d_in[6];
    const float* w_out = (const float*)d_in[7];
    const float* b_out = (const float*)d_in[8];
    const float* fc_w = (const float*)d_in[9];
    const float* fc_b = (const float*)d_in[10];
    const float* ln1_s = (const float*)d_in[11];
    const float* ln1_b = (const float*)d_in[12];
    const float* lnkv_s = (const float*)d_in[13];
    const float* lnkv_b = (const float*)d_in[14];
    const float* ln2_s = (const float*)d_in[15];
    const float* ln2_b = (const float*)d_in[16];
    const float* g1_W = (const float*)d_in[17];
    const float* g1_U = (const float*)d_in[18];
    const float* g1_bg = (const float*)d_in[19];
    const float* g2_W = (const float*)d_in[20];
    const float* g2_U = (const float*)d_in[21];
    const float* g2_bg = (const float*)d_in[22];

    float* out_f = (float*)d_out;                     // final out [4096][1024] fp32
    float* attn_f = out_f + MD_;                      // attn [N,H,L,L] fp32 (output 1)
    float* OutH = out_f;                              // h lives in out slice; h2 writes in place

    // ---- d_ws layout (u16 units) ----
    u16* WS = (u16*)d_ws;
    u16* Wop = WS;                                    // DD
    u16* Wfc = WS + (size_t)DD_;                      // DD
    u16* WQKV = WS + 2 * (size_t)DD_;                 // 16384
    u16* G1rz = WQKV + 16384;                         // 4DD
    u16* G1h  = G1rz + 4 * (size_t)DD_;               // 2DD
    u16* G2rz = G1h + 2 * (size_t)DD_;                // 4DD
    u16* G2h  = G2rz + 4 * (size_t)DD_;               // 2DD
    u16* Y    = G2h + 2 * (size_t)DD_;                // o_proj out
    u16* Xq   = Y + MD_;                              // query bf16
    u16* T1   = Xq + MD_;                             // t gate1 / reused t gate2
    u16* Hb   = T1 + MD_;                             // h bf16
    u16* F    = Hb + MD_;                             // fc out
    u16* QH   = F + MD_;
    u16* KH   = QH + MD_;
    u16* VT   = KH + MD_;
    u16* OBF  = VT + MD_;
    u16* LNQ  = OBF + MD_;
    u16* LNV  = LNQ + MD_;
    u16* LN2  = LNV + MD_;
    u16* Zb   = LN2 + MD_;                            // z bf16 [4096][1024]

    dim3 grid_n1024(M_ / 128, 8);                     // 256 blocks
    dim3 grid_n2048(M_ / 128, 16);                    // 512 blocks

    // ---- weight prep + query cvt (1 launch) ----
    prep_weights_kernel<<<9222, 256, 0, stream>>>(w_out, fc_w, wq, wk, wv,
                                                  g1_W, g1_U, g2_W, g2_U, query, Xq, WS);

    // ---- attention ----
    ln2in1_kernel<<<dim3(M_, 2), 256, 0, stream>>>(query, LNQ, ln1_s, ln1_b,
                                                   value, LNV, lnkv_s, lnkv_b);
    proj_mfma_kernel<<<dim3(32, 16), 256, 0, stream>>>(LNQ, LNV, WQKV, QH, KH, VT);
    qk_pv_kernel<<<dim3(L_ / 32, H_, N_), 512, 0, stream>>>(QH, KH, VT, mask, attn_f, OBF);
    // o_proj -> Y
    gemm_fused_kernel<0, 0, 0><<<grid_n1024, 512, 0, stream>>>(OBF, nullptr, Wop, b_out,
                                                               nullptr, nullptr, Y, nullptr, 1024);
    // GRU gate 1 (x = query -> Xq)
    gemm_fused_kernel<1, 0, 0><<<grid_n2048, 512, 0, stream>>>(Y, Xq, G1rz, g1_bg,
                                                               Xq, Zb, T1, nullptr, 2048);
    gemm_fused_kernel<2, 0, 1><<<grid_n1024, 512, 0, stream>>>(Y, T1, G1h, nullptr,
                                                               Xq, Zb, Hb, OutH, 2048);
    // LN2 + FC
    ln_kernel<<<M_, 256, 0, stream>>>(OutH, LN2, ln2_s, ln2_b);
    gemm_fused_kernel<0, 1, 0><<<grid_n1024, 512, 0, stream>>>(LN2, nullptr, Wfc, fc_b,
                                                               nullptr, nullptr, F, nullptr, 1024);
    // GRU gate 2 (x = h -> Hb)
    gemm_fused_kernel<1, 0, 0><<<grid_n2048, 512, 0, stream>>>(F, Hb, G2rz, g2_bg,
                                                               Hb, Zb, T1, nullptr, 2048);
    gemm_fused_kernel<2, 0, 0><<<grid_n1024, 512, 0, stream>>>(F, T1, G2h, nullptr,
                                                               Hb, Zb, nullptr, out_f, 2048);
}